// Round 3
// baseline (631.159 us; speedup 1.0000x reference)
//
#include <hip/hip_runtime.h>
#include <hip/hip_bf16.h>

typedef __bf16 bf16_t;
typedef __bf16 bf16x8 __attribute__((ext_vector_type(8)));
typedef float f32x4 __attribute__((ext_vector_type(4)));

#define BATCH 4
#define SEQ 4096
#define FIN 33
#define DIM 64
#define LOG2E 1.4426950408889634f

// device exp2 — one v_exp_f32
__device__ __forceinline__ float dexp2(float x) { return __builtin_amdgcn_exp2f(x); }

// ---------------- Kernel 1: q/k affine projections (fp32 math, bf16 store) ----------------
__global__ __launch_bounds__(256) void qk_proj_kernel(
    const float* __restrict__ x, const float* __restrict__ Wq,
    const float* __restrict__ bq, const float* __restrict__ Wk,
    const float* __restrict__ bk,
    bf16_t* __restrict__ qout, bf16_t* __restrict__ kout)
{
    __shared__ float sWq[FIN * DIM];
    __shared__ float sWk[FIN * DIM];
    __shared__ float sb[2 * DIM];
    const int t = threadIdx.x;
    for (int i = t; i < FIN * DIM; i += 256) { sWq[i] = Wq[i]; sWk[i] = Wk[i]; }
    if (t < DIM) { sb[t] = bq[t]; sb[DIM + t] = bk[t]; }
    __syncthreads();

    const int row = blockIdx.x * 4 + (t >> 6);   // [0, 16384)
    const int d   = t & 63;
    const float* xr = x + (size_t)row * FIN;
    float qacc = sb[d], kacc = sb[DIM + d];
#pragma unroll
    for (int f = 0; f < FIN; ++f) {
        const float xv = xr[f];                   // wave-uniform -> broadcast fetch
        qacc += xv * sWq[f * DIM + d];
        kacc += xv * sWk[f * DIM + d];
    }
    qout[(size_t)row * DIM + d] = (bf16_t)qacc;
    kout[(size_t)row * DIM + d] = (bf16_t)kacc;
}

// ---------------- Kernel 2: fused QK^T + row-max-normalized softmax ----------------
// WG = 16 rows of one batch, 8 waves (512 thr), each wave owns 512 cols.
// 3 recompute passes over cols: (1) row max, (2) Z = sum exp2(s*c - log2e), (3) write p.
// Distance-2 register pipeline on the k-tile loads for MLP.

#define NTILE 32   // 512 cols / 16 per tile

__device__ __forceinline__ f32x4 mm2(bf16x8 a0, bf16x8 a1, bf16x8 b0, bf16x8 b1)
{
    f32x4 acc = {0.f, 0.f, 0.f, 0.f};
    acc = __builtin_amdgcn_mfma_f32_16x16x32_bf16(a0, b0, acc, 0, 0, 0);
    acc = __builtin_amdgcn_mfma_f32_16x16x32_bf16(a1, b1, acc, 0, 0, 0);
    return acc;
}

#define LD(ct, h) (*reinterpret_cast<const bf16x8*>(kw + (size_t)(ct) * 16 * DIM + (h) * 32))

// Software-pipelined column loop: body(ct, acc) consumes one 16x16 score tile.
template <typename F>
__device__ __forceinline__ void col_loop(const bf16_t* __restrict__ kw,
                                         bf16x8 a0, bf16x8 a1, F&& body)
{
    bf16x8 p0a = LD(0, 0), p0b = LD(0, 1);
    bf16x8 p1a = LD(1, 0), p1b = LD(1, 1);
#pragma unroll
    for (int ct = 0; ct < NTILE; ct += 2) {
        f32x4 acc0 = mm2(a0, a1, p0a, p0b);
        if (ct + 2 < NTILE) { p0a = LD(ct + 2, 0); p0b = LD(ct + 2, 1); }
        body(ct, acc0);
        f32x4 acc1 = mm2(a0, a1, p1a, p1b);
        if (ct + 3 < NTILE) { p1a = LD(ct + 3, 0); p1b = LD(ct + 3, 1); }
        body(ct + 1, acc1);
    }
}

__global__ __launch_bounds__(512, 8) void attn_kernel(
    const bf16_t* __restrict__ qg, const bf16_t* __restrict__ kg,
    float* __restrict__ out)
{
    const int wg  = blockIdx.x;        // 0..1023
    const int b   = wg >> 8;           // batch
    const int r0  = (wg & 255) << 4;   // 16-row block within batch
    const int t   = threadIdx.x;
    const int w   = t >> 6;            // wave 0..7
    const int l   = t & 63;
    const int lr  = l & 15;            // A-row / B-col / D-col lane index
    const int kg4 = l >> 4;            // k-group; D rows kg4*4 .. +3

    const bf16_t* qbase = qg + (size_t)(b * SEQ + r0) * DIM;
    const bf16_t* kbase = kg + (size_t)b * SEQ * DIM;

    // A fragments (constant across the col loop): q[row = lr][k = kg4*8 .. +8]
    const bf16x8 a0 = *reinterpret_cast<const bf16x8*>(qbase + lr * DIM + kg4 * 8);
    const bf16x8 a1 = *reinterpret_cast<const bf16x8*>(qbase + lr * DIM + 32 + kg4 * 8);

    const int col0 = w << 9;           // 512 cols per wave
    const bf16_t* kw = kbase + (size_t)(col0 + lr) * DIM + kg4 * 8;

    __shared__ float redM[8][16];
    __shared__ float redZ[8][16];

    // ---- pass 1: row max ----
    float vmax[4] = {-3.4e38f, -3.4e38f, -3.4e38f, -3.4e38f};
    col_loop(kw, a0, a1, [&](int, f32x4 acc) {
#pragma unroll
        for (int j = 0; j < 4; ++j) vmax[j] = fmaxf(vmax[j], acc[j]);
    });
#pragma unroll
    for (int m = 1; m < 16; m <<= 1) {
#pragma unroll
        for (int j = 0; j < 4; ++j) vmax[j] = fmaxf(vmax[j], __shfl_xor(vmax[j], m, 64));
    }
    if (lr == 0) {
#pragma unroll
        for (int j = 0; j < 4; ++j) redM[w][kg4 * 4 + j] = vmax[j];
    }
    __syncthreads();
    float cM[4];                       // LOG2E / M  (TEMPERATURE = 1.0)
#pragma unroll
    for (int j = 0; j < 4; ++j) {
        const int r = kg4 * 4 + j;
        float m = redM[0][r];
#pragma unroll
        for (int ww = 1; ww < 8; ++ww) m = fmaxf(m, redM[ww][r]);
        cM[j] = LOG2E / m;
    }

    // ---- pass 2: Z = sum 2^(s*cM - log2e) ----
    float vsum[4] = {0.f, 0.f, 0.f, 0.f};
    col_loop(kw, a0, a1, [&](int, f32x4 acc) {
#pragma unroll
        for (int j = 0; j < 4; ++j) vsum[j] += dexp2(fmaf(acc[j], cM[j], -LOG2E));
    });
#pragma unroll
    for (int m = 1; m < 16; m <<= 1) {
#pragma unroll
        for (int j = 0; j < 4; ++j) vsum[j] += __shfl_xor(vsum[j], m, 64);
    }
    if (lr == 0) {
#pragma unroll
        for (int j = 0; j < 4; ++j) redZ[w][kg4 * 4 + j] = vsum[j];
    }
    __syncthreads();
    float invZ[4];
#pragma unroll
    for (int j = 0; j < 4; ++j) {
        const int r = kg4 * 4 + j;
        float z = redZ[0][r];
#pragma unroll
        for (int ww = 1; ww < 8; ++ww) z += redZ[ww][r];
        invZ[j] = 1.0f / z;
    }

    // ---- pass 3: write p = 2^(s*cM - log2e) * invZ ----
    float* orow = out + (size_t)(b * SEQ + r0 + kg4 * 4) * SEQ + col0 + lr;
    col_loop(kw, a0, a1, [&](int ct, f32x4 acc) {
#pragma unroll
        for (int j = 0; j < 4; ++j) {
            const float p = dexp2(fmaf(acc[j], cM[j], -LOG2E)) * invZ[j];
            orow[(size_t)j * SEQ + ct * 16] = p;
        }
    });
}

extern "C" void kernel_launch(void* const* d_in, const int* in_sizes, int n_in,
                              void* d_out, int out_size, void* d_ws, size_t ws_size,
                              hipStream_t stream)
{
    const float* x  = (const float*)d_in[0];
    const float* Wq = (const float*)d_in[1];
    const float* bq = (const float*)d_in[2];
    const float* Wk = (const float*)d_in[3];
    const float* bk = (const float*)d_in[4];
    float* out = (float*)d_out;

    bf16_t* qws = (bf16_t*)d_ws;
    bf16_t* kws = qws + (size_t)BATCH * SEQ * DIM;

    qk_proj_kernel<<<(BATCH * SEQ) / 4, 256, 0, stream>>>(x, Wq, bq, Wk, bk, qws, kws);
    attn_kernel<<<BATCH * (SEQ / 16), 512, 0, stream>>>(qws, kws, out);
}

// Round 5
// 211.827 us; speedup vs baseline: 2.9796x; 2.9796x over previous
//
#include <hip/hip_runtime.h>
#include <hip/hip_bf16.h>

typedef __bf16 bf16_t;
typedef __bf16 bf16x8 __attribute__((ext_vector_type(8)));
typedef float f32x4 __attribute__((ext_vector_type(4)));
typedef __fp16 f16x2 __attribute__((ext_vector_type(2)));

#define BATCH 4
#define SEQ 4096
#define FIN 33
#define DIM 64
#define LOG2E 1.4426950408889634f
#define NTILE 32   // 512 cols per wave / 16 cols per MFMA tile

__device__ __forceinline__ float dexp2(float x) { return __builtin_amdgcn_exp2f(x); }

// ---------------- Kernel 1: q/k affine projections (fp32 math, bf16 store) ----------------
__global__ __launch_bounds__(256) void qk_proj_kernel(
    const float* __restrict__ x, const float* __restrict__ Wq,
    const float* __restrict__ bq, const float* __restrict__ Wk,
    const float* __restrict__ bk,
    bf16_t* __restrict__ qout, bf16_t* __restrict__ kout)
{
    __shared__ float sWq[FIN * DIM];
    __shared__ float sWk[FIN * DIM];
    __shared__ float sb[2 * DIM];
    const int t = threadIdx.x;
    for (int i = t; i < FIN * DIM; i += 256) { sWq[i] = Wq[i]; sWk[i] = Wk[i]; }
    if (t < DIM) { sb[t] = bq[t]; sb[DIM + t] = bk[t]; }
    __syncthreads();

    const int row = blockIdx.x * 4 + (t >> 6);   // [0, 16384)
    const int d   = t & 63;
    const float* xr = x + (size_t)row * FIN;
    float qacc = sb[d], kacc = sb[DIM + d];
#pragma unroll
    for (int f = 0; f < FIN; ++f) {
        const float xv = xr[f];                   // wave-uniform -> broadcast fetch
        qacc += xv * sWq[f * DIM + d];
        kacc += xv * sWk[f * DIM + d];
    }
    qout[(size_t)row * DIM + d] = (bf16_t)qacc;
    kout[(size_t)row * DIM + d] = (bf16_t)kacc;
}

// ---------------- Kernel 2: fused QK^T + row-max-normalized softmax ----------------
// WG = 16 rows of one batch, 8 waves (512 thr), each wave owns 512 cols.
// Scores held in registers as packed fp16 (64 VGPRs/lane):
//   pass A: MFMA once, pack scores, row max
//   pass B: exp from regs, Z sum, overwrite regs with exp values
//   pass C: scale by 1/Z, store

__device__ __forceinline__ f32x4 mm2(bf16x8 a0, bf16x8 a1, bf16x8 b0, bf16x8 b1)
{
    f32x4 acc = {0.f, 0.f, 0.f, 0.f};
    acc = __builtin_amdgcn_mfma_f32_16x16x32_bf16(a0, b0, acc, 0, 0, 0);
    acc = __builtin_amdgcn_mfma_f32_16x16x32_bf16(a1, b1, acc, 0, 0, 0);
    return acc;
}

#define LD(ct, h) (*reinterpret_cast<const bf16x8*>(kw + (size_t)(ct) * 16 * DIM + (h) * 32))

__global__ __launch_bounds__(512, 4) void attn_kernel(
    const bf16_t* __restrict__ qg, const bf16_t* __restrict__ kg,
    float* __restrict__ out)
{
    const int wg  = blockIdx.x;        // 0..1023
    const int b   = wg >> 8;           // batch
    const int r0  = (wg & 255) << 4;   // 16-row block within batch
    const int t   = threadIdx.x;
    const int w   = t >> 6;            // wave 0..7
    const int l   = t & 63;
    const int lr  = l & 15;            // A-row / B-col / D-col lane index
    const int kg4 = l >> 4;            // k-group; D rows kg4*4 .. +3

    const bf16_t* qbase = qg + (size_t)(b * SEQ + r0) * DIM;
    const bf16_t* kbase = kg + (size_t)b * SEQ * DIM;

    // A fragments: q[row = lr][k = kg4*8 .. +8] (+32 for second half of K)
    const bf16x8 a0 = *reinterpret_cast<const bf16x8*>(qbase + lr * DIM + kg4 * 8);
    const bf16x8 a1 = *reinterpret_cast<const bf16x8*>(qbase + lr * DIM + 32 + kg4 * 8);

    const int col0 = w << 9;           // 512 cols per wave
    const bf16_t* kw = kbase + (size_t)(col0 + lr) * DIM + kg4 * 8;

    __shared__ float redM[8][16];
    __shared__ float redZ[8][16];

    // Score register file: s[ct][h] = packed fp16 rows (kg4*4 + 2h, +2h+1), col ct*16+lr
    f16x2 s[NTILE][2];

    // ---- pass A: MFMA once, pack scores to fp16, track row max ----
    float vmax[4] = {-3.4e38f, -3.4e38f, -3.4e38f, -3.4e38f};
    {
        bf16x8 p0a = LD(0, 0), p0b = LD(0, 1);
        bf16x8 p1a = LD(1, 0), p1b = LD(1, 1);
#pragma unroll
        for (int ct = 0; ct < NTILE; ct += 2) {
            f32x4 acc0 = mm2(a0, a1, p0a, p0b);
            if (ct + 2 < NTILE) { p0a = LD(ct + 2, 0); p0b = LD(ct + 2, 1); }
#pragma unroll
            for (int j = 0; j < 4; ++j) vmax[j] = fmaxf(vmax[j], acc0[j]);
            s[ct][0] = __builtin_amdgcn_cvt_pkrtz(acc0[0], acc0[1]);
            s[ct][1] = __builtin_amdgcn_cvt_pkrtz(acc0[2], acc0[3]);

            f32x4 acc1 = mm2(a0, a1, p1a, p1b);
            if (ct + 3 < NTILE) { p1a = LD(ct + 3, 0); p1b = LD(ct + 3, 1); }
#pragma unroll
            for (int j = 0; j < 4; ++j) vmax[j] = fmaxf(vmax[j], acc1[j]);
            s[ct + 1][0] = __builtin_amdgcn_cvt_pkrtz(acc1[0], acc1[1]);
            s[ct + 1][1] = __builtin_amdgcn_cvt_pkrtz(acc1[2], acc1[3]);
        }
    }
#pragma unroll
    for (int m = 1; m < 16; m <<= 1) {
#pragma unroll
        for (int j = 0; j < 4; ++j) vmax[j] = fmaxf(vmax[j], __shfl_xor(vmax[j], m, 64));
    }
    if (lr == 0) {
#pragma unroll
        for (int j = 0; j < 4; ++j) redM[w][kg4 * 4 + j] = vmax[j];
    }
    __syncthreads();
    float cM[4];                       // LOG2E / M  (TEMPERATURE = 1.0)
#pragma unroll
    for (int j = 0; j < 4; ++j) {
        const int r = kg4 * 4 + j;
        float m = redM[0][r];
#pragma unroll
        for (int ww = 1; ww < 8; ++ww) m = fmaxf(m, redM[ww][r]);
        cM[j] = LOG2E / m;
    }

    // ---- pass B: e = 2^(s*cM - log2e) from registers; Z sum; overwrite regs with e ----
    float vsum[4] = {0.f, 0.f, 0.f, 0.f};
#pragma unroll
    for (int ct = 0; ct < NTILE; ++ct) {
#pragma unroll
        for (int h = 0; h < 2; ++h) {
            const float e0 = dexp2(fmaf((float)s[ct][h][0], cM[2 * h + 0], -LOG2E));
            const float e1 = dexp2(fmaf((float)s[ct][h][1], cM[2 * h + 1], -LOG2E));
            vsum[2 * h + 0] += e0;
            vsum[2 * h + 1] += e1;
            s[ct][h] = __builtin_amdgcn_cvt_pkrtz(e0, e1);
        }
    }
#pragma unroll
    for (int m = 1; m < 16; m <<= 1) {
#pragma unroll
        for (int j = 0; j < 4; ++j) vsum[j] += __shfl_xor(vsum[j], m, 64);
    }
    if (lr == 0) {
#pragma unroll
        for (int j = 0; j < 4; ++j) redZ[w][kg4 * 4 + j] = vsum[j];
    }
    __syncthreads();
    float invZ[4];
#pragma unroll
    for (int j = 0; j < 4; ++j) {
        const int r = kg4 * 4 + j;
        float z = redZ[0][r];
#pragma unroll
        for (int ww = 1; ww < 8; ++ww) z += redZ[ww][r];
        invZ[j] = 1.0f / z;
    }

    // ---- pass C: p = e * invZ, store ----
    float* orow = out + (size_t)(b * SEQ + r0 + kg4 * 4) * SEQ + col0 + lr;
#pragma unroll
    for (int ct = 0; ct < NTILE; ++ct) {
#pragma unroll
        for (int h = 0; h < 2; ++h) {
            orow[(size_t)(2 * h + 0) * SEQ + ct * 16] = (float)s[ct][h][0] * invZ[2 * h + 0];
            orow[(size_t)(2 * h + 1) * SEQ + ct * 16] = (float)s[ct][h][1] * invZ[2 * h + 1];
        }
    }
}

extern "C" void kernel_launch(void* const* d_in, const int* in_sizes, int n_in,
                              void* d_out, int out_size, void* d_ws, size_t ws_size,
                              hipStream_t stream)
{
    const float* x  = (const float*)d_in[0];
    const float* Wq = (const float*)d_in[1];
    const float* bq = (const float*)d_in[2];
    const float* Wk = (const float*)d_in[3];
    const float* bk = (const float*)d_in[4];
    float* out = (float*)d_out;

    bf16_t* qws = (bf16_t*)d_ws;
    bf16_t* kws = qws + (size_t)BATCH * SEQ * DIM;

    qk_proj_kernel<<<(BATCH * SEQ) / 4, 256, 0, stream>>>(x, Wq, bq, Wk, bk, qws, kws);
    attn_kernel<<<BATCH * (SEQ / 16), 512, 0, stream>>>(qws, kws, out);
}

// Round 6
// 127.098 us; speedup vs baseline: 4.9659x; 1.6666x over previous
//
#include <hip/hip_runtime.h>
#include <hip/hip_bf16.h>

typedef __bf16 bf16_t;
typedef __bf16 bf16x8 __attribute__((ext_vector_type(8)));
typedef float f32x4 __attribute__((ext_vector_type(4)));
typedef __fp16 f16x2 __attribute__((ext_vector_type(2)));

#define BATCH 4
#define SEQ 4096
#define FIN 33
#define DIM 64
#define LOG2E 1.4426950408889634f
#define NWAVE 16   // waves per WG
#define NTILE 16   // 256 cols per wave / 16 cols per MFMA tile

__device__ __forceinline__ float dexp2(float x) { return __builtin_amdgcn_exp2f(x); }

// ---------------- Kernel 1: q/k affine projections (fp32 math, bf16 store) ----------------
__global__ __launch_bounds__(256) void qk_proj_kernel(
    const float* __restrict__ x, const float* __restrict__ Wq,
    const float* __restrict__ bq, const float* __restrict__ Wk,
    const float* __restrict__ bk,
    bf16_t* __restrict__ qout, bf16_t* __restrict__ kout)
{
    __shared__ float sWq[FIN * DIM];
    __shared__ float sWk[FIN * DIM];
    __shared__ float sb[2 * DIM];
    const int t = threadIdx.x;
    for (int i = t; i < FIN * DIM; i += 256) { sWq[i] = Wq[i]; sWk[i] = Wk[i]; }
    if (t < DIM) { sb[t] = bq[t]; sb[DIM + t] = bk[t]; }
    __syncthreads();

    const int row = blockIdx.x * 4 + (t >> 6);   // [0, 16384)
    const int d   = t & 63;
    const float* xr = x + (size_t)row * FIN;
    float qacc = sb[d], kacc = sb[DIM + d];
#pragma unroll
    for (int f = 0; f < FIN; ++f) {
        const float xv = xr[f];                   // wave-uniform -> broadcast fetch
        qacc += xv * sWq[f * DIM + d];
        kacc += xv * sWk[f * DIM + d];
    }
    qout[(size_t)row * DIM + d] = (bf16_t)qacc;
    kout[(size_t)row * DIM + d] = (bf16_t)kacc;
}

// ---------------- Kernel 2: fused QK^T + row-max-normalized softmax ----------------
// WG = 16 rows of one batch, 16 waves (1024 thr), each wave owns 256 cols.
// Scores held in registers as packed fp16 (32 VGPRs/lane):
//   pass A: MFMA once, pack scores, row max
//   pass B: exp from regs, Z sum, overwrite regs with exp values
//   pass C: scale by 1/Z, store

__device__ __forceinline__ f32x4 mm2(bf16x8 a0, bf16x8 a1, bf16x8 b0, bf16x8 b1)
{
    f32x4 acc = {0.f, 0.f, 0.f, 0.f};
    acc = __builtin_amdgcn_mfma_f32_16x16x32_bf16(a0, b0, acc, 0, 0, 0);
    acc = __builtin_amdgcn_mfma_f32_16x16x32_bf16(a1, b1, acc, 0, 0, 0);
    return acc;
}

#define LD(ct, h) (*reinterpret_cast<const bf16x8*>(kw + (size_t)(ct) * 16 * DIM + (h) * 32))

__global__ __launch_bounds__(1024, 4) void attn_kernel(
    const bf16_t* __restrict__ qg, const bf16_t* __restrict__ kg,
    float* __restrict__ out)
{
    const int wg  = blockIdx.x;        // 0..1023
    const int b   = wg >> 8;           // batch
    const int r0  = (wg & 255) << 4;   // 16-row block within batch
    const int t   = threadIdx.x;
    const int w   = t >> 6;            // wave 0..15
    const int l   = t & 63;
    const int lr  = l & 15;            // A-row / B-col / D-col lane index
    const int kg4 = l >> 4;            // k-group; D rows kg4*4 .. +3

    const bf16_t* qbase = qg + (size_t)(b * SEQ + r0) * DIM;
    const bf16_t* kbase = kg + (size_t)b * SEQ * DIM;

    // A fragments: q[row = lr][k = kg4*8 .. +8] (+32 for second half of K)
    const bf16x8 a0 = *reinterpret_cast<const bf16x8*>(qbase + lr * DIM + kg4 * 8);
    const bf16x8 a1 = *reinterpret_cast<const bf16x8*>(qbase + lr * DIM + 32 + kg4 * 8);

    const int col0 = w << 8;           // 256 cols per wave
    const bf16_t* kw = kbase + (size_t)(col0 + lr) * DIM + kg4 * 8;

    __shared__ float redM[NWAVE][16];
    __shared__ float redZ[NWAVE][16];

    // Score register file: s[ct][h] = packed fp16 rows (kg4*4 + 2h, +2h+1), col ct*16+lr
    f16x2 s[NTILE][2];

    // ---- pass A: MFMA once, pack scores to fp16, track row max ----
    float vmax[4] = {-3.4e38f, -3.4e38f, -3.4e38f, -3.4e38f};
    {
        bf16x8 p0a = LD(0, 0), p0b = LD(0, 1);
        bf16x8 p1a = LD(1, 0), p1b = LD(1, 1);
#pragma unroll
        for (int ct = 0; ct < NTILE; ct += 2) {
            f32x4 acc0 = mm2(a0, a1, p0a, p0b);
            if (ct + 2 < NTILE) { p0a = LD(ct + 2, 0); p0b = LD(ct + 2, 1); }
#pragma unroll
            for (int j = 0; j < 4; ++j) vmax[j] = fmaxf(vmax[j], acc0[j]);
            s[ct][0] = __builtin_amdgcn_cvt_pkrtz(acc0[0], acc0[1]);
            s[ct][1] = __builtin_amdgcn_cvt_pkrtz(acc0[2], acc0[3]);

            f32x4 acc1 = mm2(a0, a1, p1a, p1b);
            if (ct + 3 < NTILE) { p1a = LD(ct + 3, 0); p1b = LD(ct + 3, 1); }
#pragma unroll
            for (int j = 0; j < 4; ++j) vmax[j] = fmaxf(vmax[j], acc1[j]);
            s[ct + 1][0] = __builtin_amdgcn_cvt_pkrtz(acc1[0], acc1[1]);
            s[ct + 1][1] = __builtin_amdgcn_cvt_pkrtz(acc1[2], acc1[3]);
        }
    }
#pragma unroll
    for (int m = 1; m < 16; m <<= 1) {
#pragma unroll
        for (int j = 0; j < 4; ++j) vmax[j] = fmaxf(vmax[j], __shfl_xor(vmax[j], m, 64));
    }
    if (lr == 0) {
#pragma unroll
        for (int j = 0; j < 4; ++j) redM[w][kg4 * 4 + j] = vmax[j];
    }
    __syncthreads();
    float cM[4];                       // LOG2E / M  (TEMPERATURE = 1.0)
#pragma unroll
    for (int j = 0; j < 4; ++j) {
        const int r = kg4 * 4 + j;
        float m = redM[0][r];
#pragma unroll
        for (int ww = 1; ww < NWAVE; ++ww) m = fmaxf(m, redM[ww][r]);
        cM[j] = LOG2E / m;
    }

    // ---- pass B: e = 2^(s*cM - log2e) from registers; Z sum; overwrite regs with e ----
    float vsum[4] = {0.f, 0.f, 0.f, 0.f};
#pragma unroll
    for (int ct = 0; ct < NTILE; ++ct) {
#pragma unroll
        for (int h = 0; h < 2; ++h) {
            const float e0 = dexp2(fmaf((float)s[ct][h][0], cM[2 * h + 0], -LOG2E));
            const float e1 = dexp2(fmaf((float)s[ct][h][1], cM[2 * h + 1], -LOG2E));
            vsum[2 * h + 0] += e0;
            vsum[2 * h + 1] += e1;
            s[ct][h] = __builtin_amdgcn_cvt_pkrtz(e0, e1);
        }
    }
#pragma unroll
    for (int m = 1; m < 16; m <<= 1) {
#pragma unroll
        for (int j = 0; j < 4; ++j) vsum[j] += __shfl_xor(vsum[j], m, 64);
    }
    if (lr == 0) {
#pragma unroll
        for (int j = 0; j < 4; ++j) redZ[w][kg4 * 4 + j] = vsum[j];
    }
    __syncthreads();
    float invZ[4];
#pragma unroll
    for (int j = 0; j < 4; ++j) {
        const int r = kg4 * 4 + j;
        float z = redZ[0][r];
#pragma unroll
        for (int ww = 1; ww < NWAVE; ++ww) z += redZ[ww][r];
        invZ[j] = 1.0f / z;
    }

    // ---- pass C: p = e * invZ, store ----
    float* orow = out + (size_t)(b * SEQ + r0 + kg4 * 4) * SEQ + col0 + lr;
#pragma unroll
    for (int ct = 0; ct < NTILE; ++ct) {
#pragma unroll
        for (int h = 0; h < 2; ++h) {
            orow[(size_t)(2 * h + 0) * SEQ + ct * 16] = (float)s[ct][h][0] * invZ[2 * h + 0];
            orow[(size_t)(2 * h + 1) * SEQ + ct * 16] = (float)s[ct][h][1] * invZ[2 * h + 1];
        }
    }
}

extern "C" void kernel_launch(void* const* d_in, const int* in_sizes, int n_in,
                              void* d_out, int out_size, void* d_ws, size_t ws_size,
                              hipStream_t stream)
{
    const float* x  = (const float*)d_in[0];
    const float* Wq = (const float*)d_in[1];
    const float* bq = (const float*)d_in[2];
    const float* Wk = (const float*)d_in[3];
    const float* bk = (const float*)d_in[4];
    float* out = (float*)d_out;

    bf16_t* qws = (bf16_t*)d_ws;
    bf16_t* kws = qws + (size_t)BATCH * SEQ * DIM;

    qk_proj_kernel<<<(BATCH * SEQ) / 4, 256, 0, stream>>>(x, Wq, bq, Wk, bk, qws, kws);
    attn_kernel<<<BATCH * (SEQ / 16), 1024, 0, stream>>>(qws, kws, out);
}